// Round 2
// baseline (486.895 us; speedup 1.0000x reference)
//
#include <hip/hip_runtime.h>
#include <hip/hip_bf16.h>

// ---------------------------------------------------------------------------
// TransformerBlock: B=4, T=2048, D=1024, H=16, HD=64
// Round 10: R9's gemm256 regressed (96us vs 90) because the XCD swizzle gave
// each XCD a contiguous wg chunk spanning ALL m-tiles -> every XCD streamed
// the whole 16.8MB A matrix through its 4MB L2 (FETCH 135MB = A x 8, vs 52MB
// before). Fix: natural x-fastest mapping. Hardware round-robin then gives
// each XCD a strided ~2MB slab of A (L2-resident across the entire n-sweep)
// while concurrent blocks share B panels. Schedule (4-phase, counted
// vmcnt(8), raw s_barrier, setprio) unchanged -- isolating the mapping
// variable.
// ---------------------------------------------------------------------------

typedef __bf16 bf16;
typedef __attribute__((ext_vector_type(8))) __bf16 bf16x8;
typedef __attribute__((ext_vector_type(4))) __bf16 bf16x4;
typedef __attribute__((ext_vector_type(4))) float floatx4;

#define EXPC 0.18033688011112042f  // 0.125 * log2(e)
#define MFMA16(a, b, c) __builtin_amdgcn_mfma_f32_16x16x32_bf16(a, b, c, 0, 0, 0)

__device__ __forceinline__ void async_cp16(const bf16* g, bf16* l) {
  __builtin_amdgcn_global_load_lds(
      (const __attribute__((address_space(1))) void*)g,
      (__attribute__((address_space(3))) void*)l, 16, 0, 0);
}

// ---------------------------------------------------------------------------
// Transpose + convert: W (K x N fp32) -> WT (N x K bf16). z picks the matrix.
// ---------------------------------------------------------------------------
__global__ __launch_bounds__(256) void transpose_cvt4(
    const float* __restrict__ S0, const float* __restrict__ S1,
    const float* __restrict__ S2, const float* __restrict__ S3,
    bf16* __restrict__ D0, bf16* __restrict__ D1, bf16* __restrict__ D2,
    bf16* __restrict__ D3, int K, int N) {
  const float* W = (blockIdx.z == 0) ? S0 : (blockIdx.z == 1) ? S1
                   : (blockIdx.z == 2) ? S2 : S3;
  bf16* WT = (blockIdx.z == 0) ? D0 : (blockIdx.z == 1) ? D1
             : (blockIdx.z == 2) ? D2 : D3;
  __shared__ bf16 tile[32][33];
  const int tn = blockIdx.x;
  const int tk = blockIdx.y;
  const int t = threadIdx.x;
  const int row = t >> 3;
  const int c4 = (t & 7) * 4;

  const float* src = W + (size_t)(tk * 32 + row) * N + tn * 32 + c4;
  float4 v = *(const float4*)src;
  tile[row][c4 + 0] = (bf16)v.x;
  tile[row][c4 + 1] = (bf16)v.y;
  tile[row][c4 + 2] = (bf16)v.z;
  tile[row][c4 + 3] = (bf16)v.w;
  __syncthreads();
  bf16x4 o;
  o[0] = tile[c4 + 0][row];
  o[1] = tile[c4 + 1][row];
  o[2] = tile[c4 + 2][row];
  o[3] = tile[c4 + 3][row];
  *(bf16x4*)(WT + (size_t)(tn * 32 + row) * K + tk * 32 + c4) = o;
}

__global__ __launch_bounds__(256) void transpose_cvt(
    const float* __restrict__ W, bf16* __restrict__ WT, int K, int N) {
  __shared__ bf16 tile[32][33];
  const int tn = blockIdx.x;
  const int tk = blockIdx.y;
  const int t = threadIdx.x;
  const int row = t >> 3;
  const int c4 = (t & 7) * 4;

  const float* src = W + (size_t)(tk * 32 + row) * N + tn * 32 + c4;
  float4 v = *(const float4*)src;
  tile[row][c4 + 0] = (bf16)v.x;
  tile[row][c4 + 1] = (bf16)v.y;
  tile[row][c4 + 2] = (bf16)v.z;
  tile[row][c4 + 3] = (bf16)v.w;
  __syncthreads();
  bf16x4 o;
  o[0] = tile[c4 + 0][row];
  o[1] = tile[c4 + 1][row];
  o[2] = tile[c4 + 2][row];
  o[3] = tile[c4 + 3][row];
  *(bf16x4*)(WT + (size_t)(tn * 32 + row) * K + tk * 32 + c4) = o;
}

// ---------------------------------------------------------------------------
// V pre-transpose: V[t][d] (cols 2048.. of QKV) -> Vt[(bh*64+d)][t]
// ---------------------------------------------------------------------------
__global__ __launch_bounds__(256) void vtrans_kernel(
    const bf16* __restrict__ QKV, bf16* __restrict__ Vt) {
  const int tt = blockIdx.x;   // 0..31 t-tile
  const int bh = blockIdx.y;   // 0..63
  const int b = bh >> 4, h = bh & 15;
  __shared__ bf16 tile[64][72];
  const int t = threadIdx.x;
  const int row = t >> 3;          // 0..31
  const int c8 = (t & 7) * 8;
  const size_t vbase = (size_t)b * 2048 * 3072 + 2048 + (size_t)h * 64;
  const bf16* src = QKV + vbase + (size_t)(tt * 64 + row) * 3072 + c8;
  *(bf16x8*)&tile[row][c8] = *(const bf16x8*)src;
  *(bf16x8*)&tile[row + 32][c8] = *(const bf16x8*)(src + (size_t)32 * 3072);
  __syncthreads();
  bf16x8 o0, o1;
#pragma unroll
  for (int j = 0; j < 8; ++j) {
    o0[j] = tile[c8 + j][row];
    o1[j] = tile[c8 + j][row + 32];
  }
  bf16* dst = Vt + ((size_t)bh * 64 + row) * 2048 + tt * 64 + c8;
  *(bf16x8*)dst = o0;
  *(bf16x8*)(dst + (size_t)32 * 2048) = o1;
}

// ---------------------------------------------------------------------------
// LayerNorm: one block per row of 1024. fp32 in -> bf16 out.
// ---------------------------------------------------------------------------
__global__ __launch_bounds__(256) void ln_kernel(
    const float* __restrict__ x, const float* __restrict__ gamma,
    const float* __restrict__ beta, bf16* __restrict__ out) {
  const int row = blockIdx.x;
  const int t = threadIdx.x;
  const float* xr = x + (size_t)row * 1024;
  float4 v4 = *(const float4*)(xr + t * 4);
  float a[4] = {v4.x, v4.y, v4.z, v4.w};
  float s = a[0] + a[1] + a[2] + a[3];
  float ss = a[0] * a[0] + a[1] * a[1] + a[2] * a[2] + a[3] * a[3];
  for (int off = 1; off < 64; off <<= 1) {
    s += __shfl_xor(s, off);
    ss += __shfl_xor(ss, off);
  }
  __shared__ float red[8];
  const int wid = t >> 6, lane = t & 63;
  if (lane == 0) { red[wid] = s; red[wid + 4] = ss; }
  __syncthreads();
  s = red[0] + red[1] + red[2] + red[3];
  ss = red[4] + red[5] + red[6] + red[7];
  const float mean = s * (1.0f / 1024.0f);
  const float var = ss * (1.0f / 1024.0f) - mean * mean;
  const float rstd = rsqrtf(var + 1e-5f);
  bf16x4 o;
  for (int j = 0; j < 4; ++j) {
    float g = gamma[t * 4 + j];
    float b = beta[t * 4 + j];
    o[j] = (bf16)((a[j] - mean) * rstd * g + b);
  }
  *(bf16x4*)(out + (size_t)row * 1024 + t * 4) = o;
}

// fast exact-form tanh-gelu: gelu = x*t/(t+1), t = e^{2u}.
__device__ __forceinline__ float gelu_f(float x) {
  const float c = 0.7978845608028654f;
  float u = c * (x + 0.044715f * x * x * x);
  u = fminf(fmaxf(u, -10.0f), 10.0f);
  float t = __builtin_exp2f(u * 2.8853900817779268f);  // e^{2u}
  return x * t * __builtin_amdgcn_rcpf(t + 1.0f);
}

// ---------------------------------------------------------------------------
// GEMM (256 thr, 4 waves 2x2, each 64x64): C[M,N] = A[M,K] @ BT[N,K]^T.
// 128x128 tile, templated BK. Used for the N=1024 GEMMs (Wo, W2) where a
// 256^2 grid would be starved (128 blocks).
// MODE 1: bf16 = gelu(C+bias); MODE 2: f32 = C+bias+resid; MODE 3: bf16 = C.
// ---------------------------------------------------------------------------
template <int MODE, int BK>
__global__ __launch_bounds__(256, 2) void gemm_bt(
    const bf16* __restrict__ A, const bf16* __restrict__ BT,
    const float* __restrict__ bias, const float* __restrict__ resid,
    void* __restrict__ out, int M, int N, int K) {
  __shared__ bf16 sA[128 * BK];
  __shared__ bf16 sB[128 * BK];
  constexpr int GPR = BK / 8;
  constexpr int CPT = GPR / 2;
  constexpr int RPI = 256 / GPR;
  constexpr int SW = (BK >= 64) ? 7 : 0;

  const int t = threadIdx.x;
  const int lane = t & 63, wid = t >> 6;
  const int waveM = wid >> 1, waveN = wid & 1;
  const int quad = lane >> 4, l16 = lane & 15;
  const size_t m0 = (size_t)blockIdx.x * 128;
  const size_t n0 = (size_t)blockIdx.y * 128;

  floatx4 acc[4][4] = {};

  const int r0 = t / GPR;
  const int gp = t % GPR;
  const int gsrc = gp ^ (r0 & SW);
  const bf16* Ag = A + (m0 + r0) * (size_t)K + gsrc * 8;
  const bf16* Bg = BT + (n0 + r0) * (size_t)K + gsrc * 8;
  bf16* sAp = sA + t * 8;
  bf16* sBp = sB + t * 8;

  for (int k0 = 0; k0 < K; k0 += BK) {
    __syncthreads();
#pragma unroll
    for (int it = 0; it < CPT; ++it) {
      async_cp16(Ag + k0 + (size_t)(it * RPI) * K, sAp + it * 2048);
      async_cp16(Bg + k0 + (size_t)(it * RPI) * K, sBp + it * 2048);
    }
    __syncthreads();
#pragma unroll
    for (int ks = 0; ks < BK / 32; ++ks) {
      bf16x8 af[4], bfv[4];
#pragma unroll
      for (int i = 0; i < 4; ++i) {
        const int rowA = waveM * 64 + i * 16 + l16;
        const int g = ((ks * 4 + quad) ^ (l16 & SW)) * 8;
        af[i] = *(const bf16x8*)&sA[rowA * BK + g];
        const int rowB = waveN * 64 + i * 16 + l16;
        bfv[i] = *(const bf16x8*)&sB[rowB * BK + g];
      }
#pragma unroll
      for (int mt = 0; mt < 4; ++mt)
#pragma unroll
        for (int nt = 0; nt < 4; ++nt)
          acc[mt][nt] = __builtin_amdgcn_mfma_f32_16x16x32_bf16(
              af[mt], bfv[nt], acc[mt][nt], 0, 0, 0);
    }
  }

#pragma unroll
  for (int mt = 0; mt < 4; ++mt) {
#pragma unroll
    for (int nt = 0; nt < 4; ++nt) {
      const size_t row_base = m0 + waveM * 64 + mt * 16 + quad * 4;
      const size_t col = n0 + waveN * 64 + nt * 16 + l16;
#pragma unroll
      for (int r = 0; r < 4; ++r) {
        const size_t row = row_base + r;
        float v = acc[mt][nt][r];
        if (MODE == 1) {
          v = gelu_f(v + bias[col]);
          ((bf16*)out)[row * N + col] = (bf16)v;
        } else if (MODE == 2) {
          v += bias[col] + resid[row * N + col];
          ((float*)out)[row * N + col] = v;
        } else {
          ((bf16*)out)[row * N + col] = (bf16)v;
        }
      }
    }
  }
}

// ---------------------------------------------------------------------------
// gemm256: 256x256 tile, BK=64, 512 thr = 8 waves (2M x 4N), per-wave 128x64.
// 4 phases per K-tile, 16 MFMA each:
//   P0: ds_read A-frags 0-3 + B-frags 0-1 | bar | lgkm0 | MFMA Q(0-3 x 0-1)
//   P1: ds_read B-frags 2-3              | bar | lgkm0 | MFMA Q(0-3 x 2-3)
//   P2: ds_read A-frags 4-7, issue B half-tiles of K-tile t+2 (B region of
//       this buffer fully read after P1's closing barrier) | bar | lgkm0 |
//       MFMA Q(4-7 x 0-1)
//   P3: issue A half-tiles of t+2 (A region free after P2's closing barrier)
//       | bar | MFMA Q(4-7 x 2-3) | s_waitcnt vmcnt(8) | bar
// Counted vmcnt: at each tile boundary exactly 8 loads (t+2's stages) stay
// in flight while t+1's 8 are drained. Raw s_barrier everywhere so the DMA
// queue is never force-drained. LDS 2 x (256x64 A + 256x64 B) = 128 KiB.
// Block mapping: NATURAL x-fastest (m-tile fastest). HW round-robin then
// gives each XCD a strided ~2MB slab of A that stays L2-resident for the
// whole n-sweep (R9's contiguous-chunk swizzle thrashed: FETCH = A x 8).
// ---------------------------------------------------------------------------
template <int MODE>
__global__ __launch_bounds__(512, 2) void gemm256(
    const bf16* __restrict__ A, const bf16* __restrict__ BT,
    const float* __restrict__ bias, const float* __restrict__ resid,
    void* __restrict__ out, int M, int N, int K) {
  __shared__ bf16 sA[2][256 * 64];
  __shared__ bf16 sB[2][256 * 64];

  const int t = threadIdx.x;
  const int lane = t & 63;
  const int wid = t >> 6;          // 0..7
  const int wm = wid >> 2;         // 0..1  (M half)
  const int wn = wid & 3;          // 0..3  (N quarter)
  const int quad = lane >> 4, l16 = lane & 15;

  // natural mapping: m-tile = x (fastest in dispatch order)
  const size_t m0 = (size_t)blockIdx.x * 256;
  const size_t n0 = (size_t)blockIdx.y * 256;

  // staging: thread t covers row r0 (of 64 per load), 16B group gp, source
  // group pre-swizzled so LDS group g holds global group g^(r&7).
  const int r0 = t >> 3;           // 0..63
  const int gp = t & 7;
  const int gsw = gp ^ (r0 & 7);
  const bf16* Ag = A + (m0 + r0) * (size_t)K + gsw * 8;
  const bf16* Bg = BT + (n0 + r0) * (size_t)K + gsw * 8;

  auto stageA = [&](int d, int kt, int h) {
    async_cp16(Ag + (size_t)(h * 128) * K + kt * 64,
               &sA[d][(h * 128) * 64 + t * 8]);
    async_cp16(Ag + (size_t)(h * 128 + 64) * K + kt * 64,
               &sA[d][(h * 128 + 64) * 64 + t * 8]);
  };
  auto stageB = [&](int d, int kt, int h) {
    async_cp16(Bg + (size_t)(h * 128) * K + kt * 64,
               &sB[d][(h * 128) * 64 + t * 8]);
    async_cp16(Bg + (size_t)(h * 128 + 64) * K + kt * 64,
               &sB[d][(h * 128 + 64) * 64 + t * 8]);
  };

  const int NT = K >> 6;  // K-tiles of 64

  // prologue: K-tile 0 -> buf0 (8 loads), K-tile 1 -> buf1 (8 loads)
  stageA(0, 0, 0); stageA(0, 0, 1); stageB(0, 0, 0); stageB(0, 0, 1);
  stageA(1, 1, 0); stageA(1, 1, 1); stageB(1, 1, 0); stageB(1, 1, 1);
  asm volatile("s_waitcnt vmcnt(8)" ::: "memory");  // K-tile 0 landed
  __builtin_amdgcn_sched_barrier(0);
  __builtin_amdgcn_s_barrier();

  floatx4 acc[8][4] = {};
  bf16x8 afv[4][2], bfv[4][2];

  for (int kt = 0; kt < NT; ++kt) {
    const int d = kt & 1;
    const bf16* sAd = sA[d];
    const bf16* sBd = sB[d];
    const bool pf = (kt + 2 < NT);

    // ---------------- phase 0 ----------------
#pragma unroll
    for (int mf = 0; mf < 4; ++mf) {
      const int row = wm * 128 + mf * 16 + l16;
#pragma unroll
      for (int ks = 0; ks < 2; ++ks)
        afv[mf][ks] = *(const bf16x8*)
            &sAd[row * 64 + (((ks * 4 + quad) ^ (row & 7)) << 3)];
    }
#pragma unroll
    for (int nf = 0; nf < 2; ++nf) {
      const int col = wn * 64 + nf * 16 + l16;
#pragma unroll
      for (int ks = 0; ks < 2; ++ks)
        bfv[nf][ks] = *(const bf16x8*)
            &sBd[col * 64 + (((ks * 4 + quad) ^ (col & 7)) << 3)];
    }
    __builtin_amdgcn_s_barrier();
    asm volatile("s_waitcnt lgkmcnt(0)" ::: "memory");
    __builtin_amdgcn_sched_barrier(0);
    __builtin_amdgcn_s_setprio(1);
#pragma unroll
    for (int mf = 0; mf < 4; ++mf)
#pragma unroll
      for (int nf = 0; nf < 2; ++nf) {
        acc[mf][nf] = MFMA16(afv[mf][0], bfv[nf][0], acc[mf][nf]);
        acc[mf][nf] = MFMA16(afv[mf][1], bfv[nf][1], acc[mf][nf]);
      }
    __builtin_amdgcn_s_setprio(0);
    __builtin_amdgcn_s_barrier();

    // ---------------- phase 1 ----------------
#pragma unroll
    for (int nf = 2; nf < 4; ++nf) {
      const int col = wn * 64 + nf * 16 + l16;
#pragma unroll
      for (int ks = 0; ks < 2; ++ks)
        bfv[nf][ks] = *(const bf16x8*)
            &sBd[col * 64 + (((ks * 4 + quad) ^ (col & 7)) << 3)];
    }
    __builtin_amdgcn_s_barrier();
    asm volatile("s_waitcnt lgkmcnt(0)" ::: "memory");
    __builtin_amdgcn_sched_barrier(0);
    __builtin_amdgcn_s_setprio(1);
#pragma unroll
    for (int mf = 0; mf < 4; ++mf)
#pragma unroll
      for (int nf = 2; nf < 4; ++nf) {
        acc[mf][nf] = MFMA16(afv[mf][0], bfv[nf][0], acc[mf][nf]);
        acc[mf][nf] = MFMA16(afv[mf][1], bfv[nf][1], acc[mf][nf]);
      }
    __builtin_amdgcn_s_setprio(0);
    __builtin_amdgcn_s_barrier();

    // ---------------- phase 2 ----------------
    // B region of this buffer is fully consumed (P0+P1 drained before the
    // P1 closing barrier) -> safe to issue t+2's B half-tiles here.
#pragma unroll
    for (int mf = 0; mf < 4; ++mf) {
      const int row = wm * 128 + 64 + mf * 16 + l16;
#pragma unroll
      for (int ks = 0; ks < 2; ++ks)
        afv[mf][ks] = *(const bf16x8*)
            &sAd[row * 64 + (((ks * 4 + quad) ^ (row & 7)) << 3)];
    }
    if (pf) { stageB(d, kt + 2, 0); stageB(d, kt + 2, 1); }
    __builtin_amdgcn_s_barrier();
    asm volatile("s_waitcnt lgkmcnt(0)" ::: "memory");
    __builtin_amdgcn_sched_barrier(0);
    __builtin_amdgcn_s_setprio(1);
#pragma unroll
    for (int mf = 0; mf < 4; ++mf)
#pragma unroll
      for (int nf = 0; nf < 2; ++nf) {
        acc[4 + mf][nf] = MFMA16(afv[mf][0], bfv[nf][0], acc[4 + mf][nf]);
        acc[4 + mf][nf] = MFMA16(afv[mf][1], bfv[nf][1], acc[4 + mf][nf]);
      }
    __builtin_amdgcn_s_setprio(0);
    __builtin_amdgcn_s_barrier();

    // ---------------- phase 3 ----------------
    // A region fully consumed (P0+P2 drained before P2 closing barrier).
    if (pf) { stageA(d, kt + 2, 0); stageA(d, kt + 2, 1); }
    __builtin_amdgcn_s_barrier();
    __builtin_amdgcn_s_setprio(1);
#pragma unroll
    for (int mf = 0; mf < 4; ++mf)
#pragma unroll
      for (int nf = 2; nf < 4; ++nf) {
        acc[4 + mf][nf] = MFMA16(afv[mf][0], bfv[nf][0], acc[4 + mf][nf]);
        acc[4 + mf][nf] = MFMA16(afv[mf][1], bfv[nf][1], acc[4 + mf][nf]);
      }
    __builtin_amdgcn_s_setprio(0);
    // boundary: drain K-tile t+1's 8 loads; keep t+2's 8 in flight.
    if (pf) {
      asm volatile("s_waitcnt vmcnt(8)" ::: "memory");
    } else if (kt + 1 < NT) {
      asm volatile("s_waitcnt vmcnt(0)" ::: "memory");
    }
    __builtin_amdgcn_sched_barrier(0);
    __builtin_amdgcn_s_barrier();
  }

  // epilogue
#pragma unroll
  for (int mf = 0; mf < 8; ++mf) {
#pragma unroll
    for (int nf = 0; nf < 4; ++nf) {
      const size_t row_base = m0 + wm * 128 + mf * 16 + quad * 4;
      const size_t col = n0 + wn * 64 + nf * 16 + l16;
#pragma unroll
      for (int r = 0; r < 4; ++r) {
        const size_t row = row_base + r;
        float v = acc[mf][nf][r];
        if (MODE == 1) {
          v = gelu_f(v + bias[col]);
          ((bf16*)out)[row * N + col] = (bf16)v;
        } else if (MODE == 2) {
          v += bias[col] + resid[row * N + col];
          ((float*)out)[row * N + col] = v;
        } else {
          ((bf16*)out)[row * N + col] = (bf16)v;
        }
      }
    }
  }
}

// ---------------------------------------------------------------------------
// Flash-style causal attention, QT=128, S^T orientation, DMA staging.
// ---------------------------------------------------------------------------
__global__ __launch_bounds__(256) void attn_kernel(
    const bf16* __restrict__ QKV, const bf16* __restrict__ Vt,
    bf16* __restrict__ O) {
  const int idx = blockIdx.x;
  const int qt = 15 - (idx >> 6);  // big q-tiles dispatch first
  const int bh = idx & 63;
  const int b = bh >> 4, h = bh & 15;
  const int t = threadIdx.x;
  const int lane = t & 63, wid = t >> 6;
  const int quad = lane >> 4, l16 = lane & 15;

  __shared__ bf16 sQ[128 * 64];   // swizzled rows (q-major)
  __shared__ bf16 sK[64 * 64];    // swizzled rows (key-major)
  __shared__ bf16 sV[64 * 64];    // swizzled rows (d-major, from Vt)
  __shared__ bf16 sP[4][16][72];  // [wave][q][key]

  const size_t qkvbase = (size_t)b * 2048 * 3072 + (size_t)h * 64;
  const int q0 = qt * 128;

  const int r0 = t >> 3;   // 0..31
  const int gp = t & 7;
  const int gsw = gp ^ (r0 & 7);  // (r0+32)&7 == r0&7: same for both halves

  // one-time Q stage via DMA (128 rows x 64)
  {
    const bf16* pQ = QKV + qkvbase + (size_t)(q0 + r0) * 3072 + gsw * 8;
#pragma unroll
    for (int j = 0; j < 4; ++j)
      async_cp16(pQ + (size_t)(j * 32) * 3072, sQ + j * 2048 + t * 8);
  }

  // K/V staging pointers (bumped per k-tile)
  const bf16* pK = QKV + qkvbase + 1024 + (size_t)r0 * 3072 + gsw * 8;
  const bf16* pV = Vt + ((size_t)bh * 64 + r0) * 2048 + gsw * 8;
  const ptrdiff_t bumpK = (ptrdiff_t)64 * 3072;

  __syncthreads();  // drain Q DMA

  // Q B-fragments: lane n=q, k-chunk = d
  bf16x8 aq[2][2];
#pragma unroll
  for (int mt = 0; mt < 2; ++mt) {
    const int row = wid * 32 + mt * 16 + l16;
#pragma unroll
    for (int ks = 0; ks < 2; ++ks)
      aq[mt][ks] =
          *(const bf16x8*)&sQ[row * 64 + (((ks * 4 + quad) ^ (row & 7)) * 8)];
  }

  float l_part[2] = {0.f, 0.f};
  floatx4 o_acc[2][4] = {};

  const int ktmax = 2 * qt + 1;
  for (int kt = 0; kt <= ktmax; ++kt) {
    __syncthreads();  // prior reads of sK/sV done
    async_cp16(pK, sK + t * 8);
    async_cp16(pK + (size_t)32 * 3072, sK + 2048 + t * 8);
    async_cp16(pV, sV + t * 8);
    async_cp16(pV + (size_t)32 * 2048, sV + 2048 + t * 8);
    pK += bumpK;
    pV += 64;
    __syncthreads();  // drain DMA

    // V B-fragments (lane n=d), read once, reused across mt
    bf16x8 bv[4][2];
#pragma unroll
    for (int nt = 0; nt < 4; ++nt) {
      const int d = nt * 16 + l16;
#pragma unroll
      for (int ks = 0; ks < 2; ++ks)
        bv[nt][ks] =
            *(const bf16x8*)&sV[d * 64 + (((ks * 4 + quad) ^ (d & 7)) * 8)];
    }

    // S^T = K-frag x Q-frag: D rows = keys, cols = q
    float p[2][4][4];
#pragma unroll
    for (int nt = 0; nt < 4; ++nt) {
      const int kr = nt * 16 + l16;
      bf16x8 bk0 = *(const bf16x8*)&sK[kr * 64 + ((quad ^ (kr & 7)) * 8)];
      bf16x8 bk1 = *(const bf16x8*)&sK[kr * 64 + (((4 + quad) ^ (kr & 7)) * 8)];
#pragma unroll
      for (int mt = 0; mt < 2; ++mt) {
        floatx4 acc = {};
        acc = __builtin_amdgcn_mfma_f32_16x16x32_bf16(bk0, aq[mt][0], acc, 0, 0, 0);
        acc = __builtin_amdgcn_mfma_f32_16x16x32_bf16(bk1, aq[mt][1], acc, 0, 0, 0);
#pragma unroll
        for (int r = 0; r < 4; ++r)
          p[mt][nt][r] = __builtin_exp2f(acc[r] * EXPC);
      }
    }

    // causal mask on the last two k-tiles: zero where key > q
    if (kt >= ktmax - 1) {
      const int k0 = kt * 64;
#pragma unroll
      for (int mt = 0; mt < 2; ++mt) {
        const int qg = q0 + wid * 32 + mt * 16 + l16;
#pragma unroll
        for (int nt = 0; nt < 4; ++nt) {
          const int kg = k0 + nt * 16 + quad * 4;
#pragma unroll
          for (int r = 0; r < 4; ++r)
            if (kg + r > qg) p[mt][nt][r] = 0.f;
        }
      }
    }

#pragma unroll
    for (int mt = 0; mt < 2; ++mt) {
      // P -> sP: lane (quad,l16) holds P[q=l16][key=nt*16+quad*4+r] -> b64
#pragma unroll
      for (int nt = 0; nt < 4; ++nt) {
        bf16x4 pk;
#pragma unroll
        for (int r = 0; r < 4; ++r) {
          l_part[mt] += p[mt][nt][r];
          pk[r] = (bf16)p[mt][nt][r];
        }
        *(bf16x4*)&sP[wid][l16][nt * 16 + quad * 4] = pk;
      }
      // A-frag for PV (same-wave LDS ordering; sP[wid] wave-private)
      bf16x8 ap0 = *(const bf16x8*)&sP[wid][l16][quad * 8];
      bf16x8 ap1 = *(const bf16x8*)&sP[wid][l16][32 + quad * 8];
#pragma unroll
      for (int nt = 0; nt < 4; ++nt) {
        o_acc[mt][nt] = __builtin_amdgcn_mfma_f32_16x16x32_bf16(
            ap0, bv[nt][0], o_acc[mt][nt], 0, 0, 0);
        o_acc[mt][nt] = __builtin_amdgcn_mfma_f32_16x16x32_bf16(
            ap1, bv[nt][1], o_acc[mt][nt], 0, 0, 0);
      }
    }
  }

  // l reduce (across quads) + broadcast to o_acc rows + write O
#pragma unroll
  for (int mt = 0; mt < 2; ++mt) {
    float lt = l_part[mt];
    lt += __shfl_xor(lt, 16);
    lt += __shfl_xor(lt, 32);  // every lane: total for q = wid*32+mt*16+l16
    float inv[4];
#pragma unroll
    for (int r = 0; r < 4; ++r)
      inv[r] = 1.0f / __shfl(lt, quad * 4 + r);  // l for q-row quad*4+r
#pragma unroll
    for (int nt = 0; nt < 4; ++nt)
#pragma unroll
      for (int r = 0; r < 4; ++r) {
        const size_t row =
            (size_t)b * 2048 + q0 + wid * 32 + mt * 16 + quad * 4 + r;
        const size_t col = (size_t)h * 64 + nt * 16 + l16;
        O[row * 1024 + col] = (bf16)(o_acc[mt][nt][r] * inv[r]);
      }
  }
}

// ---------------------------------------------------------------------------
// Launch
// ---------------------------------------------------------------------------
extern "C" void kernel_launch(void* const* d_in, const int* in_sizes, int n_in,
                              void* d_out, int out_size, void* d_ws, size_t ws_size,
                              hipStream_t stream) {
  const float* x = (const float*)d_in[0];
  const float* Wq = (const float*)d_in[1];
  const float* Wk = (const float*)d_in[2];
  const float* Wv = (const float*)d_in[3];
  const float* Wo = (const float*)d_in[4];
  const float* bo = (const float*)d_in[5];
  const float* W1 = (const float*)d_in[6];
  const float* b1 = (const float*)d_in[7];
  const float* W2 = (const float*)d_in[8];
  const float* b2 = (const float*)d_in[9];
  const float* gamma1 = (const float*)d_in[10];
  const float* beta1 = (const float*)d_in[11];
  const float* gamma2 = (const float*)d_in[12];
  const float* beta2 = (const float*)d_in[13];

  char* ws = (char*)d_ws;
  const size_t MB = (size_t)1 << 20;
  bf16* WqkvT = (bf16*)(ws + 0 * MB);
  bf16* WoT = (bf16*)(ws + 6 * MB);
  bf16* W1T = (bf16*)(ws + 8 * MB);
  bf16* W2T = (bf16*)(ws + 16 * MB);
  bf16* h1  = (bf16*)(ws + 24 * MB);   // reused as Vt after QKV GEMM
  bf16* Vt  = (bf16*)(ws + 24 * MB);   // 64*64*2048*2 = 16MB
  bf16* QKVb = (bf16*)(ws + 40 * MB);
  bf16* attnb = (bf16*)(ws + 88 * MB);
  float* x1 = (float*)(ws + 104 * MB);
  bf16* h2  = (bf16*)(ws + 136 * MB);
  bf16* midb = (bf16*)(ws + 152 * MB);

  dim3 blk(256);

  transpose_cvt4<<<dim3(32, 32, 4), blk, 0, stream>>>(
      Wq, Wk, Wv, Wo, WqkvT, WqkvT + (size_t)1024 * 1024,
      WqkvT + (size_t)2048 * 1024, WoT, 1024, 1024);
  transpose_cvt<<<dim3(128, 32), blk, 0, stream>>>(W1, W1T, 1024, 4096);
  transpose_cvt<<<dim3(32, 128), blk, 0, stream>>>(W2, W2T, 4096, 1024);

  ln_kernel<<<8192, blk, 0, stream>>>(x, gamma1, beta1, h1);

  // fused QKV projection: [Q|K|V] = h1 @ [Wq|Wk|Wv]  (256^2 4-phase)
  gemm256<3><<<dim3(32, 12), dim3(512), 0, stream>>>(
      h1, WqkvT, nullptr, nullptr, QKVb, 8192, 3072, 1024);

  // V -> Vt (overwrites h1, which is dead after the QKV GEMM)
  vtrans_kernel<<<dim3(32, 64), blk, 0, stream>>>(QKVb, Vt);

  attn_kernel<<<dim3(1024), blk, 0, stream>>>(QKVb, Vt, attnb);

  // x1 = x + attn @ Wo + bo  (N=1024: keep 128^2, BK=128)
  gemm_bt<2, 128><<<dim3(64, 8), blk, 0, stream>>>(attnb, WoT, bo, x, x1,
                                                   8192, 1024, 1024);

  ln_kernel<<<8192, blk, 0, stream>>>(x1, gamma2, beta2, h2);

  // mid = gelu(h2 @ W1 + b1)  (256^2 4-phase, fast gelu epilogue)
  gemm256<1><<<dim3(32, 16), dim3(512), 0, stream>>>(
      h2, W1T, b1, nullptr, midb, 8192, 4096, 1024);

  // out = x1 + mid @ W2 + b2  (N=1024: keep 128^2, BK=128)
  gemm_bt<2, 128><<<dim3(64, 8), blk, 0, stream>>>(midb, W2T, b2, x1, d_out,
                                                   8192, 1024, 4096);
}

// Round 3
// 479.798 us; speedup vs baseline: 1.0148x; 1.0148x over previous
//
#include <hip/hip_runtime.h>
#include <hip/hip_bf16.h>

// ---------------------------------------------------------------------------
// TransformerBlock: B=4, T=2048, D=1024, H=16, HD=64
// Round 11: gemm256 (4-phase 256^2) reverted -- two rounds confirmed it is
// schedule-stall-bound at 589 TF (m232 failure band) regardless of memory
// behavior; proven gemm_bt (763 TF, 3 blocks/CU implicit overlap) restored
// for all GEMMs. This round's variable: attn K/V staging converted from
// [sync][DMA][sync-drain] to T14 issue-early/complete-late: fragments are
// read to regs first, then next tile's DMA issues BEFORE compute, with
// per-wave counted vmcnt(0)+barrier at the next iteration top. DMA latency
// hides under the ~1000+cyc compute phase. Same barrier count, same LDS,
// same occupancy (3 blocks/CU).
// ---------------------------------------------------------------------------

typedef __bf16 bf16;
typedef __attribute__((ext_vector_type(8))) __bf16 bf16x8;
typedef __attribute__((ext_vector_type(4))) __bf16 bf16x4;
typedef __attribute__((ext_vector_type(4))) float floatx4;

#define EXPC 0.18033688011112042f  // 0.125 * log2(e)

__device__ __forceinline__ void async_cp16(const bf16* g, bf16* l) {
  __builtin_amdgcn_global_load_lds(
      (const __attribute__((address_space(1))) void*)g,
      (__attribute__((address_space(3))) void*)l, 16, 0, 0);
}

// ---------------------------------------------------------------------------
// Transpose + convert: W (K x N fp32) -> WT (N x K bf16). z picks the matrix.
// ---------------------------------------------------------------------------
__global__ __launch_bounds__(256) void transpose_cvt4(
    const float* __restrict__ S0, const float* __restrict__ S1,
    const float* __restrict__ S2, const float* __restrict__ S3,
    bf16* __restrict__ D0, bf16* __restrict__ D1, bf16* __restrict__ D2,
    bf16* __restrict__ D3, int K, int N) {
  const float* W = (blockIdx.z == 0) ? S0 : (blockIdx.z == 1) ? S1
                   : (blockIdx.z == 2) ? S2 : S3;
  bf16* WT = (blockIdx.z == 0) ? D0 : (blockIdx.z == 1) ? D1
             : (blockIdx.z == 2) ? D2 : D3;
  __shared__ bf16 tile[32][33];
  const int tn = blockIdx.x;
  const int tk = blockIdx.y;
  const int t = threadIdx.x;
  const int row = t >> 3;
  const int c4 = (t & 7) * 4;

  const float* src = W + (size_t)(tk * 32 + row) * N + tn * 32 + c4;
  float4 v = *(const float4*)src;
  tile[row][c4 + 0] = (bf16)v.x;
  tile[row][c4 + 1] = (bf16)v.y;
  tile[row][c4 + 2] = (bf16)v.z;
  tile[row][c4 + 3] = (bf16)v.w;
  __syncthreads();
  bf16x4 o;
  o[0] = tile[c4 + 0][row];
  o[1] = tile[c4 + 1][row];
  o[2] = tile[c4 + 2][row];
  o[3] = tile[c4 + 3][row];
  *(bf16x4*)(WT + (size_t)(tn * 32 + row) * K + tk * 32 + c4) = o;
}

__global__ __launch_bounds__(256) void transpose_cvt(
    const float* __restrict__ W, bf16* __restrict__ WT, int K, int N) {
  __shared__ bf16 tile[32][33];
  const int tn = blockIdx.x;
  const int tk = blockIdx.y;
  const int t = threadIdx.x;
  const int row = t >> 3;
  const int c4 = (t & 7) * 4;

  const float* src = W + (size_t)(tk * 32 + row) * N + tn * 32 + c4;
  float4 v = *(const float4*)src;
  tile[row][c4 + 0] = (bf16)v.x;
  tile[row][c4 + 1] = (bf16)v.y;
  tile[row][c4 + 2] = (bf16)v.z;
  tile[row][c4 + 3] = (bf16)v.w;
  __syncthreads();
  bf16x4 o;
  o[0] = tile[c4 + 0][row];
  o[1] = tile[c4 + 1][row];
  o[2] = tile[c4 + 2][row];
  o[3] = tile[c4 + 3][row];
  *(bf16x4*)(WT + (size_t)(tn * 32 + row) * K + tk * 32 + c4) = o;
}

// ---------------------------------------------------------------------------
// V pre-transpose: V[t][d] (cols 2048.. of QKV) -> Vt[(bh*64+d)][t]
// ---------------------------------------------------------------------------
__global__ __launch_bounds__(256) void vtrans_kernel(
    const bf16* __restrict__ QKV, bf16* __restrict__ Vt) {
  const int tt = blockIdx.x;   // 0..31 t-tile
  const int bh = blockIdx.y;   // 0..63
  const int b = bh >> 4, h = bh & 15;
  __shared__ bf16 tile[64][72];
  const int t = threadIdx.x;
  const int row = t >> 3;          // 0..31
  const int c8 = (t & 7) * 8;
  const size_t vbase = (size_t)b * 2048 * 3072 + 2048 + (size_t)h * 64;
  const bf16* src = QKV + vbase + (size_t)(tt * 64 + row) * 3072 + c8;
  *(bf16x8*)&tile[row][c8] = *(const bf16x8*)src;
  *(bf16x8*)&tile[row + 32][c8] = *(const bf16x8*)(src + (size_t)32 * 3072);
  __syncthreads();
  bf16x8 o0, o1;
#pragma unroll
  for (int j = 0; j < 8; ++j) {
    o0[j] = tile[c8 + j][row];
    o1[j] = tile[c8 + j][row + 32];
  }
  bf16* dst = Vt + ((size_t)bh * 64 + row) * 2048 + tt * 64 + c8;
  *(bf16x8*)dst = o0;
  *(bf16x8*)(dst + (size_t)32 * 2048) = o1;
}

// ---------------------------------------------------------------------------
// LayerNorm: one block per row of 1024. fp32 in -> bf16 out.
// ---------------------------------------------------------------------------
__global__ __launch_bounds__(256) void ln_kernel(
    const float* __restrict__ x, const float* __restrict__ gamma,
    const float* __restrict__ beta, bf16* __restrict__ out) {
  const int row = blockIdx.x;
  const int t = threadIdx.x;
  const float* xr = x + (size_t)row * 1024;
  float4 v4 = *(const float4*)(xr + t * 4);
  float a[4] = {v4.x, v4.y, v4.z, v4.w};
  float s = a[0] + a[1] + a[2] + a[3];
  float ss = a[0] * a[0] + a[1] * a[1] + a[2] * a[2] + a[3] * a[3];
  for (int off = 1; off < 64; off <<= 1) {
    s += __shfl_xor(s, off);
    ss += __shfl_xor(ss, off);
  }
  __shared__ float red[8];
  const int wid = t >> 6, lane = t & 63;
  if (lane == 0) { red[wid] = s; red[wid + 4] = ss; }
  __syncthreads();
  s = red[0] + red[1] + red[2] + red[3];
  ss = red[4] + red[5] + red[6] + red[7];
  const float mean = s * (1.0f / 1024.0f);
  const float var = ss * (1.0f / 1024.0f) - mean * mean;
  const float rstd = rsqrtf(var + 1e-5f);
  bf16x4 o;
  for (int j = 0; j < 4; ++j) {
    float g = gamma[t * 4 + j];
    float b = beta[t * 4 + j];
    o[j] = (bf16)((a[j] - mean) * rstd * g + b);
  }
  *(bf16x4*)(out + (size_t)row * 1024 + t * 4) = o;
}

// fast exact-form tanh-gelu: gelu = x*t/(t+1), t = e^{2u}.
__device__ __forceinline__ float gelu_f(float x) {
  const float c = 0.7978845608028654f;
  float u = c * (x + 0.044715f * x * x * x);
  u = fminf(fmaxf(u, -10.0f), 10.0f);
  float t = __builtin_exp2f(u * 2.8853900817779268f);  // e^{2u}
  return x * t * __builtin_amdgcn_rcpf(t + 1.0f);
}

// ---------------------------------------------------------------------------
// GEMM (256 thr, 4 waves 2x2, each 64x64): C[M,N] = A[M,K] @ BT[N,K]^T.
// 128x128 tile, templated BK: 64 block-rich (3 blocks/CU), 128 grid-starved.
// BK>=64: 16B groups XOR-swizzled via the global gather (LDS dst linear).
// MODE 1: bf16 = gelu(C+bias); MODE 2: f32 = C+bias+resid; MODE 3: bf16 = C.
// ---------------------------------------------------------------------------
template <int MODE, int BK>
__global__ __launch_bounds__(256, 2) void gemm_bt(
    const bf16* __restrict__ A, const bf16* __restrict__ BT,
    const float* __restrict__ bias, const float* __restrict__ resid,
    void* __restrict__ out, int M, int N, int K) {
  __shared__ bf16 sA[128 * BK];
  __shared__ bf16 sB[128 * BK];
  constexpr int GPR = BK / 8;
  constexpr int CPT = GPR / 2;
  constexpr int RPI = 256 / GPR;
  constexpr int SW = (BK >= 64) ? 7 : 0;

  const int t = threadIdx.x;
  const int lane = t & 63, wid = t >> 6;
  const int waveM = wid >> 1, waveN = wid & 1;
  const int quad = lane >> 4, l16 = lane & 15;
  const size_t m0 = (size_t)blockIdx.x * 128;
  const size_t n0 = (size_t)blockIdx.y * 128;

  floatx4 acc[4][4] = {};

  const int r0 = t / GPR;
  const int gp = t % GPR;
  const int gsrc = gp ^ (r0 & SW);
  const bf16* Ag = A + (m0 + r0) * (size_t)K + gsrc * 8;
  const bf16* Bg = BT + (n0 + r0) * (size_t)K + gsrc * 8;
  bf16* sAp = sA + t * 8;
  bf16* sBp = sB + t * 8;

  for (int k0 = 0; k0 < K; k0 += BK) {
    __syncthreads();
#pragma unroll
    for (int it = 0; it < CPT; ++it) {
      async_cp16(Ag + k0 + (size_t)(it * RPI) * K, sAp + it * 2048);
      async_cp16(Bg + k0 + (size_t)(it * RPI) * K, sBp + it * 2048);
    }
    __syncthreads();
#pragma unroll
    for (int ks = 0; ks < BK / 32; ++ks) {
      bf16x8 af[4], bfv[4];
#pragma unroll
      for (int i = 0; i < 4; ++i) {
        const int rowA = waveM * 64 + i * 16 + l16;
        const int g = ((ks * 4 + quad) ^ (l16 & SW)) * 8;
        af[i] = *(const bf16x8*)&sA[rowA * BK + g];
        const int rowB = waveN * 64 + i * 16 + l16;
        bfv[i] = *(const bf16x8*)&sB[rowB * BK + g];
      }
#pragma unroll
      for (int mt = 0; mt < 4; ++mt)
#pragma unroll
        for (int nt = 0; nt < 4; ++nt)
          acc[mt][nt] = __builtin_amdgcn_mfma_f32_16x16x32_bf16(
              af[mt], bfv[nt], acc[mt][nt], 0, 0, 0);
    }
  }

#pragma unroll
  for (int mt = 0; mt < 4; ++mt) {
#pragma unroll
    for (int nt = 0; nt < 4; ++nt) {
      const size_t row_base = m0 + waveM * 64 + mt * 16 + quad * 4;
      const size_t col = n0 + waveN * 64 + nt * 16 + l16;
#pragma unroll
      for (int r = 0; r < 4; ++r) {
        const size_t row = row_base + r;
        float v = acc[mt][nt][r];
        if (MODE == 1) {
          v = gelu_f(v + bias[col]);
          ((bf16*)out)[row * N + col] = (bf16)v;
        } else if (MODE == 2) {
          v += bias[col] + resid[row * N + col];
          ((float*)out)[row * N + col] = v;
        } else {
          ((bf16*)out)[row * N + col] = (bf16)v;
        }
      }
    }
  }
}

// ---------------------------------------------------------------------------
// Flash-style causal attention, QT=128, S^T orientation, DMA staging.
// Per wave: 32 q-rows (2 mt). QK as S^T = K-frag x Q-frag: C-layout gives
// lane=q, regs=4 consecutive keys -> sP written as b64, l-sum per-lane.
// R11: T14 issue-early/complete-late staging. Per 64-key tile:
//   [vmcnt(0)+bar: tile data landed (all waves)] -> read bv/bk frags to regs
//   -> lgkm0+bar (buffers free) -> issue DMA for tile t+1 -> compute
// DMA latency hides under the QK/exp/sP/PV compute phase.
// LDS: sQ 16K + sK 8K + sV 8K + sP 9K = 41KB -> 3 blocks/CU.
// ---------------------------------------------------------------------------
__global__ __launch_bounds__(256) void attn_kernel(
    const bf16* __restrict__ QKV, const bf16* __restrict__ Vt,
    bf16* __restrict__ O) {
  const int idx = blockIdx.x;
  const int qt = 15 - (idx >> 6);  // big q-tiles dispatch first
  const int bh = idx & 63;
  const int b = bh >> 4, h = bh & 15;
  const int t = threadIdx.x;
  const int lane = t & 63, wid = t >> 6;
  const int quad = lane >> 4, l16 = lane & 15;

  __shared__ bf16 sQ[128 * 64];   // swizzled rows (q-major)
  __shared__ bf16 sK[64 * 64];    // swizzled rows (key-major)
  __shared__ bf16 sV[64 * 64];    // swizzled rows (d-major, from Vt)
  __shared__ bf16 sP[4][16][72];  // [wave][q][key]

  const size_t qkvbase = (size_t)b * 2048 * 3072 + (size_t)h * 64;
  const int q0 = qt * 128;

  const int r0 = t >> 3;   // 0..31
  const int gp = t & 7;
  const int gsw = gp ^ (r0 & 7);  // (r0+32)&7 == r0&7: same for both halves

  // one-time Q stage via DMA (128 rows x 64)
  {
    const bf16* pQ = QKV + qkvbase + (size_t)(q0 + r0) * 3072 + gsw * 8;
#pragma unroll
    for (int j = 0; j < 4; ++j)
      async_cp16(pQ + (size_t)(j * 32) * 3072, sQ + j * 2048 + t * 8);
  }

  // K/V staging pointers (bumped per k-tile)
  const bf16* pK = QKV + qkvbase + 1024 + (size_t)r0 * 3072 + gsw * 8;
  const bf16* pV = Vt + ((size_t)bh * 64 + r0) * 2048 + gsw * 8;
  const ptrdiff_t bumpK = (ptrdiff_t)64 * 3072;

  // stage K/V tile 0 alongside Q
  async_cp16(pK, sK + t * 8);
  async_cp16(pK + (size_t)32 * 3072, sK + 2048 + t * 8);
  async_cp16(pV, sV + t * 8);
  async_cp16(pV + (size_t)32 * 2048, sV + 2048 + t * 8);
  pK += bumpK;
  pV += 64;

  __syncthreads();  // drain Q + K/V tile-0 DMA

  // Q B-fragments: lane n=q, k-chunk = d
  bf16x8 aq[2][2];
#pragma unroll
  for (int mt = 0; mt < 2; ++mt) {
    const int row = wid * 32 + mt * 16 + l16;
#pragma unroll
    for (int ks = 0; ks < 2; ++ks)
      aq[mt][ks] =
          *(const bf16x8*)&sQ[row * 64 + (((ks * 4 + quad) ^ (row & 7)) * 8)];
  }

  float l_part[2] = {0.f, 0.f};
  floatx4 o_acc[2][4] = {};

  const int ktmax = 2 * qt + 1;
  for (int kt = 0; kt <= ktmax; ++kt) {
    if (kt) {
      // tile kt's DMA (issued during tile kt-1's compute) fully landed:
      // own-wave vmcnt(0) + barrier = union over all waves.
      asm volatile("s_waitcnt vmcnt(0)" ::: "memory");
      __builtin_amdgcn_sched_barrier(0);
      __builtin_amdgcn_s_barrier();
    }

    // read ALL K/V fragments to registers (sK/sV dead afterwards)
    bf16x8 bv[4][2], bkf[4][2];
#pragma unroll
    for (int nt = 0; nt < 4; ++nt) {
      const int d = nt * 16 + l16;
#pragma unroll
      for (int ks = 0; ks < 2; ++ks)
        bv[nt][ks] =
            *(const bf16x8*)&sV[d * 64 + (((ks * 4 + quad) ^ (d & 7)) * 8)];
      const int kr = nt * 16 + l16;  // == d, kept for clarity
      bkf[nt][0] = *(const bf16x8*)&sK[kr * 64 + ((quad ^ (kr & 7)) * 8)];
      bkf[nt][1] = *(const bf16x8*)&sK[kr * 64 + (((4 + quad) ^ (kr & 7)) * 8)];
    }
    asm volatile("s_waitcnt lgkmcnt(0)" ::: "memory");
    __builtin_amdgcn_sched_barrier(0);
    __builtin_amdgcn_s_barrier();  // all waves' frag reads complete

    // issue next tile's DMA; latency hides under the compute below
    if (kt < ktmax) {
      async_cp16(pK, sK + t * 8);
      async_cp16(pK + (size_t)32 * 3072, sK + 2048 + t * 8);
      async_cp16(pV, sV + t * 8);
      async_cp16(pV + (size_t)32 * 2048, sV + 2048 + t * 8);
      pK += bumpK;
      pV += 64;
    }

    // S^T = K-frag x Q-frag: D rows = keys, cols = q
    float p[2][4][4];
#pragma unroll
    for (int nt = 0; nt < 4; ++nt) {
#pragma unroll
      for (int mt = 0; mt < 2; ++mt) {
        floatx4 acc = {};
        acc = __builtin_amdgcn_mfma_f32_16x16x32_bf16(bkf[nt][0], aq[mt][0],
                                                      acc, 0, 0, 0);
        acc = __builtin_amdgcn_mfma_f32_16x16x32_bf16(bkf[nt][1], aq[mt][1],
                                                      acc, 0, 0, 0);
#pragma unroll
        for (int r = 0; r < 4; ++r)
          p[mt][nt][r] = __builtin_exp2f(acc[r] * EXPC);
      }
    }

    // causal mask on the last two k-tiles: zero where key > q
    if (kt >= ktmax - 1) {
      const int k0 = kt * 64;
#pragma unroll
      for (int mt = 0; mt < 2; ++mt) {
        const int qg = q0 + wid * 32 + mt * 16 + l16;
#pragma unroll
        for (int nt = 0; nt < 4; ++nt) {
          const int kg = k0 + nt * 16 + quad * 4;
#pragma unroll
          for (int r = 0; r < 4; ++r)
            if (kg + r > qg) p[mt][nt][r] = 0.f;
        }
      }
    }

#pragma unroll
    for (int mt = 0; mt < 2; ++mt) {
      // P -> sP: lane (quad,l16) holds P[q=l16][key=nt*16+quad*4+r] -> b64
#pragma unroll
      for (int nt = 0; nt < 4; ++nt) {
        bf16x4 pk;
#pragma unroll
        for (int r = 0; r < 4; ++r) {
          l_part[mt] += p[mt][nt][r];
          pk[r] = (bf16)p[mt][nt][r];
        }
        *(bf16x4*)&sP[wid][l16][nt * 16 + quad * 4] = pk;
      }
      // A-frag for PV (same-wave LDS ordering; sP[wid] wave-private)
      bf16x8 ap0 = *(const bf16x8*)&sP[wid][l16][quad * 8];
      bf16x8 ap1 = *(const bf16x8*)&sP[wid][l16][32 + quad * 8];
#pragma unroll
      for (int nt = 0; nt < 4; ++nt) {
        o_acc[mt][nt] = __builtin_amdgcn_mfma_f32_16x16x32_bf16(
            ap0, bv[nt][0], o_acc[mt][nt], 0, 0, 0);
        o_acc[mt][nt] = __builtin_amdgcn_mfma_f32_16x16x32_bf16(
            ap1, bv[nt][1], o_acc[mt][nt], 0, 0, 0);
      }
    }
  }

  // l reduce (across quads) + broadcast to o_acc rows + write O
#pragma unroll
  for (int mt = 0; mt < 2; ++mt) {
    float lt = l_part[mt];
    lt += __shfl_xor(lt, 16);
    lt += __shfl_xor(lt, 32);  // every lane: total for q = wid*32+mt*16+l16
    float inv[4];
#pragma unroll
    for (int r = 0; r < 4; ++r)
      inv[r] = 1.0f / __shfl(lt, quad * 4 + r);  // l for q-row quad*4+r
#pragma unroll
    for (int nt = 0; nt < 4; ++nt)
#pragma unroll
      for (int r = 0; r < 4; ++r) {
        const size_t row =
            (size_t)b * 2048 + q0 + wid * 32 + mt * 16 + quad * 4 + r;
        const size_t col = (size_t)h * 64 + nt * 16 + l16;
        O[row * 1024 + col] = (bf16)(o_acc[mt][nt][r] * inv[r]);
      }
  }
}

// ---------------------------------------------------------------------------
// Launch
// ---------------------------------------------------------------------------
extern "C" void kernel_launch(void* const* d_in, const int* in_sizes, int n_in,
                              void* d_out, int out_size, void* d_ws, size_t ws_size,
                              hipStream_t stream) {
  const float* x = (const float*)d_in[0];
  const float* Wq = (const float*)d_in[1];
  const float* Wk = (const float*)d_in[2];
  const float* Wv = (const float*)d_in[3];
  const float* Wo = (const float*)d_in[4];
  const float* bo = (const float*)d_in[5];
  const float* W1 = (const float*)d_in[6];
  const float* b1 = (const float*)d_in[7];
  const float* W2 = (const float*)d_in[8];
  const float* b2 = (const float*)d_in[9];
  const float* gamma1 = (const float*)d_in[10];
  const float* beta1 = (const float*)d_in[11];
  const float* gamma2 = (const float*)d_in[12];
  const float* beta2 = (const float*)d_in[13];

  char* ws = (char*)d_ws;
  const size_t MB = (size_t)1 << 20;
  bf16* WqkvT = (bf16*)(ws + 0 * MB);
  bf16* WoT = (bf16*)(ws + 6 * MB);
  bf16* W1T = (bf16*)(ws + 8 * MB);
  bf16* W2T = (bf16*)(ws + 16 * MB);
  bf16* h1  = (bf16*)(ws + 24 * MB);   // reused as Vt after QKV GEMM
  bf16* Vt  = (bf16*)(ws + 24 * MB);   // 64*64*2048*2 = 16MB
  bf16* QKVb = (bf16*)(ws + 40 * MB);
  bf16* attnb = (bf16*)(ws + 88 * MB);
  float* x1 = (float*)(ws + 104 * MB);
  bf16* h2  = (bf16*)(ws + 136 * MB);
  bf16* midb = (bf16*)(ws + 152 * MB);

  dim3 blk(256);

  transpose_cvt4<<<dim3(32, 32, 4), blk, 0, stream>>>(
      Wq, Wk, Wv, Wo, WqkvT, WqkvT + (size_t)1024 * 1024,
      WqkvT + (size_t)2048 * 1024, WoT, 1024, 1024);
  transpose_cvt<<<dim3(128, 32), blk, 0, stream>>>(W1, W1T, 1024, 4096);
  transpose_cvt<<<dim3(32, 128), blk, 0, stream>>>(W2, W2T, 4096, 1024);

  ln_kernel<<<8192, blk, 0, stream>>>(x, gamma1, beta1, h1);

  // fused QKV projection: [Q|K|V] = h1 @ [Wq|Wk|Wv]  (block-rich: BK=64)
  gemm_bt<3, 64><<<dim3(64, 24), blk, 0, stream>>>(h1, WqkvT, nullptr, nullptr,
                                                   QKVb, 8192, 3072, 1024);

  // V -> Vt (overwrites h1, which is dead after the QKV GEMM)
  vtrans_kernel<<<dim3(32, 64), blk, 0, stream>>>(QKVb, Vt);

  attn_kernel<<<dim3(1024), blk, 0, stream>>>(QKVb, Vt, attnb);

  // x1 = x + attn @ Wo + bo  (grid-starved: BK=128)
  gemm_bt<2, 128><<<dim3(64, 8), blk, 0, stream>>>(attnb, WoT, bo, x, x1,
                                                   8192, 1024, 1024);

  ln_kernel<<<8192, blk, 0, stream>>>(x1, gamma2, beta2, h2);

  // mid = gelu(h2 @ W1 + b1)  (block-rich: BK=64, fast gelu)
  gemm_bt<1, 64><<<dim3(64, 32), blk, 0, stream>>>(h2, W1T, b1, nullptr, midb,
                                                   8192, 4096, 1024);

  // out = x1 + mid @ W2 + b2  (grid-starved: BK=128)
  gemm_bt<2, 128><<<dim3(64, 8), blk, 0, stream>>>(midb, W2T, b2, x1, d_out,
                                                   8192, 1024, 4096);
}